// Round 2
// baseline (151.566 us; speedup 1.0000x reference)
//
#include <hip/hip_runtime.h>

#define B_ 2
#define C_ 4
#define H_ 512
#define W_ 512
#define V_ 100000
#define F_ 200000
#define A_ 8

#define HW_   (H_ * W_)                 // 262144
#define NPIX  (B_ * C_ * H_ * W_)       // 2,097,152
#define PLANE ((size_t)NPIX * 3)

// ---------------------------------------------------------------------------
// Kernel 1: face normals.  fn[b][f] = cross(v1-v0, v2-v0)   (B*F*3 floats)
// ---------------------------------------------------------------------------
__global__ void k_face_normal(const float* __restrict__ vertex_pos,
                              const int* __restrict__ faces,
                              float* __restrict__ face_normal) {
    int t = blockIdx.x * blockDim.x + threadIdx.x;
    if (t >= B_ * F_) return;
    int b = t / F_;
    int f = t - b * F_;
    int i0 = faces[f * 3 + 0];
    int i1 = faces[f * 3 + 1];
    int i2 = faces[f * 3 + 2];
    const float* vp = vertex_pos + (size_t)b * V_ * 3;
    float p0x = vp[i0 * 3 + 0], p0y = vp[i0 * 3 + 1], p0z = vp[i0 * 3 + 2];
    float p1x = vp[i1 * 3 + 0], p1y = vp[i1 * 3 + 1], p1z = vp[i1 * 3 + 2];
    float p2x = vp[i2 * 3 + 0], p2y = vp[i2 * 3 + 1], p2z = vp[i2 * 3 + 2];
    float e1x = p1x - p0x, e1y = p1y - p0y, e1z = p1z - p0z;
    float e2x = p2x - p0x, e2y = p2y - p0y, e2z = p2z - p0z;
    face_normal[(size_t)t * 3 + 0] = e1y * e2z - e1z * e2y;
    face_normal[(size_t)t * 3 + 1] = e1z * e2x - e1x * e2z;
    face_normal[(size_t)t * 3 + 2] = e1x * e2y - e1y * e2x;
}

// ---------------------------------------------------------------------------
// Kernel 2: faces as int4 (one 16B gather in the pixel kernel)
// ---------------------------------------------------------------------------
__global__ void k_faces4(const int* __restrict__ faces, int4* __restrict__ faces4) {
    int t = blockIdx.x * blockDim.x + threadIdx.x;
    if (t >= F_) return;
    faces4[t] = make_int4(faces[t * 3 + 0], faces[t * 3 + 1], faces[t * 3 + 2], 0);
}

// ---------------------------------------------------------------------------
// Kernel 3: packed pos+normal table.
//   pn[(b*V+v)*2+0] = {pos.x, pos.y, pos.z, nrm.x}
//   pn[(b*V+v)*2+1] = {nrm.y, nrm.z, 0, 0}
// ---------------------------------------------------------------------------
__global__ void k_pn(const float* __restrict__ vertex_pos,
                     const float* __restrict__ face_normal,
                     const int* __restrict__ vert_adj_faces,
                     const float* __restrict__ vert_adj_weights,
                     float4* __restrict__ pn) {
    int t = blockIdx.x * blockDim.x + threadIdx.x;
    if (t >= B_ * V_) return;
    int b = t / V_;
    int v = t - b * V_;
    const int* adj = vert_adj_faces + (size_t)v * A_;
    const float* wt = vert_adj_weights + (size_t)v * A_;
    const float* fn = face_normal + (size_t)b * F_ * 3;
    float ax = 0.f, ay = 0.f, az = 0.f;
#pragma unroll
    for (int a = 0; a < A_; ++a) {
        int f = adj[a];
        float w = wt[a];
        ax += w * fn[(size_t)f * 3 + 0];
        ay += w * fn[(size_t)f * 3 + 1];
        az += w * fn[(size_t)f * 3 + 2];
    }
    const float* p = vertex_pos + (size_t)t * 3;
    pn[(size_t)t * 2 + 0] = make_float4(p[0], p[1], p[2], ax);
    pn[(size_t)t * 2 + 1] = make_float4(ay, az, 0.f, 0.f);
}

// ---------------------------------------------------------------------------
// Kernel 4: packed screen-space table.  scr[bc*V+v] = {ix/iz, iy/iz, iz, 0}
// ---------------------------------------------------------------------------
__global__ void k_scr(const float* __restrict__ vertex_pos,
                      const float* __restrict__ intrinsics,
                      const float* __restrict__ extrinsics,
                      float4* __restrict__ scr) {
    int t = blockIdx.x * blockDim.x + threadIdx.x;
    if (t >= B_ * C_ * V_) return;
    int v = t % V_;
    int bc = t / V_;
    int b = bc / C_;
    const float* vp = vertex_pos + ((size_t)b * V_ + v) * 3;
    float x = vp[0], y = vp[1], z = vp[2];
    const float* E = extrinsics + (size_t)bc * 12;
    float cv0 = x * E[0] + y * E[1] + z * E[2]  + E[3];
    float cv1 = x * E[4] + y * E[5] + z * E[6]  + E[7];
    float cv2 = x * E[8] + y * E[9] + z * E[10] + E[11];
    const float* K = intrinsics + (size_t)bc * 9;
    float i0 = cv0 * K[0] + cv1 * K[1] + cv2 * K[2];
    float i1 = cv0 * K[3] + cv1 * K[4] + cv2 * K[5];
    float i2 = cv0 * K[6] + cv1 * K[7] + cv2 * K[8];
    scr[t] = make_float4(i0 / i2, i1 / i2, i2, 0.f);
}

// ---------------------------------------------------------------------------
// Kernel 5: per-pixel shading, 4 pixels per thread, float4-coalesced I/O.
// ---------------------------------------------------------------------------
__global__ void k_pixel4(const int4* __restrict__ faces4,
                         const float* __restrict__ inverse_extrinsics,
                         const int* __restrict__ face_id,
                         const float* __restrict__ bary,
                         const float4* __restrict__ pn,
                         const float4* __restrict__ scr,
                         float* __restrict__ out) {
    int t = blockIdx.x * blockDim.x + threadIdx.x;
    if (t >= NPIX / 4) return;
    int p0 = t * 4;
    int bc = p0 / HW_;
    int b = bc / C_;

    // camera origin for this view
    const float* ie = inverse_extrinsics + (size_t)bc * 16;
    float iw = ie[15];
    float ox = ie[3] / iw, oy = ie[7] / iw, oz = ie[11] / iw;

    int4 fid4 = *(const int4*)(face_id + p0);
    int fidv[4] = {fid4.x, fid4.y, fid4.z, fid4.w};

    const float4* bb = (const float4*)(bary + (size_t)p0 * 3);
    float4 bw0 = bb[0], bw1 = bb[1], bw2 = bb[2];
    float bw[12] = {bw0.x, bw0.y, bw0.z, bw0.w,
                    bw1.x, bw1.y, bw1.z, bw1.w,
                    bw2.x, bw2.y, bw2.z, bw2.w};

    float fg[4], dep[4];
    float pos[4][3], nrm[4][3], sc[4][3];

#pragma unroll
    for (int k = 0; k < 4; ++k) {
        int fid = fidv[k];
        float w0 = bw[3 * k + 0], w1 = bw[3 * k + 1], w2 = bw[3 * k + 2];
        if (fid >= 0) {
            int4 f = faces4[fid];
            size_t base = (size_t)b * V_;
            float4 a0 = pn[(base + f.x) * 2 + 0];
            float4 a1 = pn[(base + f.x) * 2 + 1];
            float4 b0 = pn[(base + f.y) * 2 + 0];
            float4 b1 = pn[(base + f.y) * 2 + 1];
            float4 c0 = pn[(base + f.z) * 2 + 0];
            float4 c1 = pn[(base + f.z) * 2 + 1];
            size_t sbase = (size_t)bc * V_;
            float4 s0 = scr[sbase + f.x];
            float4 s1 = scr[sbase + f.y];
            float4 s2 = scr[sbase + f.z];

            float px = w0 * a0.x + w1 * b0.x + w2 * c0.x;
            float py = w0 * a0.y + w1 * b0.y + w2 * c0.y;
            float pz = w0 * a0.z + w1 * b0.z + w2 * c0.z;
            float nx = w0 * a0.w + w1 * b0.w + w2 * c0.w;
            float ny = w0 * a1.x + w1 * b1.x + w2 * c1.x;
            float nz = w0 * a1.y + w1 * b1.y + w2 * c1.y;
            float sx = w0 * s0.x + w1 * s1.x + w2 * s2.x;
            float sy = w0 * s0.y + w1 * s1.y + w2 * s2.y;
            float sz = w0 * s0.z + w1 * s1.z + w2 * s2.z;

            float nlen = fmaxf(sqrtf(nx * nx + ny * ny + nz * nz), 1e-12f);
            nx /= nlen; ny /= nlen; nz /= nlen;

            float dx = ox - px, dy = oy - py, dz = oz - pz;
            float dd = sqrtf(dx * dx + dy * dy + dz * dz);

            fg[k] = 1.f; dep[k] = dd;
            pos[k][0] = px; pos[k][1] = py; pos[k][2] = pz;
            nrm[k][0] = nx; nrm[k][1] = ny; nrm[k][2] = nz;
            sc[k][0] = sx; sc[k][1] = sy; sc[k][2] = sz;
        } else {
            fg[k] = 0.f; dep[k] = 0.f;
            pos[k][0] = pos[k][1] = pos[k][2] = 0.f;
            nrm[k][0] = nrm[k][1] = nrm[k][2] = 0.f;
            sc[k][0] = sc[k][1] = sc[k][2] = 0.f;
        }
    }

    size_t o = (size_t)p0 * 3;
    // plane 0: fg broadcast to 3 ch
    {
        float4* w = (float4*)(out + 0 * PLANE + o);
        w[0] = make_float4(fg[0], fg[0], fg[0], fg[1]);
        w[1] = make_float4(fg[1], fg[1], fg[2], fg[2]);
        w[2] = make_float4(fg[2], fg[3], fg[3], fg[3]);
    }
    // plane 1: pos
    {
        float4* w = (float4*)(out + 1 * PLANE + o);
        w[0] = make_float4(pos[0][0], pos[0][1], pos[0][2], pos[1][0]);
        w[1] = make_float4(pos[1][1], pos[1][2], pos[2][0], pos[2][1]);
        w[2] = make_float4(pos[2][2], pos[3][0], pos[3][1], pos[3][2]);
    }
    // plane 2: nrm
    {
        float4* w = (float4*)(out + 2 * PLANE + o);
        w[0] = make_float4(nrm[0][0], nrm[0][1], nrm[0][2], nrm[1][0]);
        w[1] = make_float4(nrm[1][1], nrm[1][2], nrm[2][0], nrm[2][1]);
        w[2] = make_float4(nrm[2][2], nrm[3][0], nrm[3][1], nrm[3][2]);
    }
    // plane 3: depth broadcast to 3 ch
    {
        float4* w = (float4*)(out + 3 * PLANE + o);
        w[0] = make_float4(dep[0], dep[0], dep[0], dep[1]);
        w[1] = make_float4(dep[1], dep[1], dep[2], dep[2]);
        w[2] = make_float4(dep[2], dep[3], dep[3], dep[3]);
    }
    // plane 4: scr
    {
        float4* w = (float4*)(out + 4 * PLANE + o);
        w[0] = make_float4(sc[0][0], sc[0][1], sc[0][2], sc[1][0]);
        w[1] = make_float4(sc[1][1], sc[1][2], sc[2][0], sc[2][1]);
        w[2] = make_float4(sc[2][2], sc[3][0], sc[3][1], sc[3][2]);
    }
}

// ---------------------------------------------------------------------------
// Fallback path (round-1 kernels) if ws is too small for the packed tables.
// ---------------------------------------------------------------------------
__global__ void k_vertex_normal(const float* __restrict__ face_normal,
                                const int* __restrict__ vert_adj_faces,
                                const float* __restrict__ vert_adj_weights,
                                float* __restrict__ vertex_normal) {
    int t = blockIdx.x * blockDim.x + threadIdx.x;
    if (t >= B_ * V_) return;
    int b = t / V_;
    int v = t - b * V_;
    const int* adj = vert_adj_faces + (size_t)v * A_;
    const float* wt = vert_adj_weights + (size_t)v * A_;
    const float* fn = face_normal + (size_t)b * F_ * 3;
    float ax = 0.f, ay = 0.f, az = 0.f;
#pragma unroll
    for (int a = 0; a < A_; ++a) {
        int f = adj[a];
        float w = wt[a];
        ax += w * fn[(size_t)f * 3 + 0];
        ay += w * fn[(size_t)f * 3 + 1];
        az += w * fn[(size_t)f * 3 + 2];
    }
    vertex_normal[(size_t)t * 3 + 0] = ax;
    vertex_normal[(size_t)t * 3 + 1] = ay;
    vertex_normal[(size_t)t * 3 + 2] = az;
}

__global__ void k_project(const float* __restrict__ vertex_pos,
                          const float* __restrict__ intrinsics,
                          const float* __restrict__ extrinsics,
                          float* __restrict__ iv) {
    int t = blockIdx.x * blockDim.x + threadIdx.x;
    if (t >= B_ * C_ * V_) return;
    int v = t % V_;
    int bc = t / V_;
    int b = bc / C_;
    const float* vp = vertex_pos + ((size_t)b * V_ + v) * 3;
    float x = vp[0], y = vp[1], z = vp[2];
    const float* E = extrinsics + (size_t)bc * 12;
    float cv0 = x * E[0] + y * E[1] + z * E[2]  + E[3];
    float cv1 = x * E[4] + y * E[5] + z * E[6]  + E[7];
    float cv2 = x * E[8] + y * E[9] + z * E[10] + E[11];
    const float* K = intrinsics + (size_t)bc * 9;
    float i0 = cv0 * K[0] + cv1 * K[1] + cv2 * K[2];
    float i1 = cv0 * K[3] + cv1 * K[4] + cv2 * K[5];
    float i2 = cv0 * K[6] + cv1 * K[7] + cv2 * K[8];
    float* o = iv + (size_t)t * 3;
    o[0] = i0 / i2;
    o[1] = i1 / i2;
    o[2] = i2;
}

__global__ void k_pixel(const float* __restrict__ vertex_pos,
                        const int* __restrict__ faces,
                        const float* __restrict__ inverse_extrinsics,
                        const int* __restrict__ face_id,
                        const float* __restrict__ bary,
                        const float* __restrict__ vertex_normal,
                        const float* __restrict__ iv,
                        float* __restrict__ out) {
    int p = blockIdx.x * blockDim.x + threadIdx.x;
    if (p >= NPIX) return;
    int bc = p / HW_;
    int b = bc / C_;
    int fid = face_id[p];
    float fg = 0.f, px = 0.f, py = 0.f, pz = 0.f, nx = 0.f, ny = 0.f, nz = 0.f;
    float dd = 0.f, sx = 0.f, sy = 0.f, sz = 0.f;
    if (fid >= 0) {
        int i0 = faces[fid * 3 + 0];
        int i1 = faces[fid * 3 + 1];
        int i2 = faces[fid * 3 + 2];
        float w0 = bary[(size_t)p * 3 + 0];
        float w1 = bary[(size_t)p * 3 + 1];
        float w2 = bary[(size_t)p * 3 + 2];
        const float* vp = vertex_pos    + (size_t)b  * V_ * 3;
        const float* vn = vertex_normal + (size_t)b  * V_ * 3;
        const float* sv = iv            + (size_t)bc * V_ * 3;
        px = w0 * vp[i0 * 3 + 0] + w1 * vp[i1 * 3 + 0] + w2 * vp[i2 * 3 + 0];
        py = w0 * vp[i0 * 3 + 1] + w1 * vp[i1 * 3 + 1] + w2 * vp[i2 * 3 + 1];
        pz = w0 * vp[i0 * 3 + 2] + w1 * vp[i1 * 3 + 2] + w2 * vp[i2 * 3 + 2];
        nx = w0 * vn[i0 * 3 + 0] + w1 * vn[i1 * 3 + 0] + w2 * vn[i2 * 3 + 0];
        ny = w0 * vn[i0 * 3 + 1] + w1 * vn[i1 * 3 + 1] + w2 * vn[i2 * 3 + 1];
        nz = w0 * vn[i0 * 3 + 2] + w1 * vn[i1 * 3 + 2] + w2 * vn[i2 * 3 + 2];
        sx = w0 * sv[i0 * 3 + 0] + w1 * sv[i1 * 3 + 0] + w2 * sv[i2 * 3 + 0];
        sy = w0 * sv[i0 * 3 + 1] + w1 * sv[i1 * 3 + 1] + w2 * sv[i2 * 3 + 1];
        sz = w0 * sv[i0 * 3 + 2] + w1 * sv[i1 * 3 + 2] + w2 * sv[i2 * 3 + 2];
        float nlen = fmaxf(sqrtf(nx * nx + ny * ny + nz * nz), 1e-12f);
        nx /= nlen; ny /= nlen; nz /= nlen;
        const float* ie = inverse_extrinsics + (size_t)bc * 16;
        float iw = ie[15];
        float dx = ie[3] / iw - px, dy = ie[7] / iw - py, dz = ie[11] / iw - pz;
        dd = sqrtf(dx * dx + dy * dy + dz * dz);
        fg = 1.f;
    }
    size_t o = (size_t)p * 3;
    out[0 * PLANE + o + 0] = fg; out[0 * PLANE + o + 1] = fg; out[0 * PLANE + o + 2] = fg;
    out[1 * PLANE + o + 0] = px; out[1 * PLANE + o + 1] = py; out[1 * PLANE + o + 2] = pz;
    out[2 * PLANE + o + 0] = nx; out[2 * PLANE + o + 1] = ny; out[2 * PLANE + o + 2] = nz;
    out[3 * PLANE + o + 0] = dd; out[3 * PLANE + o + 1] = dd; out[3 * PLANE + o + 2] = dd;
    out[4 * PLANE + o + 0] = sx; out[4 * PLANE + o + 1] = sy; out[4 * PLANE + o + 2] = sz;
}

// ---------------------------------------------------------------------------
extern "C" void kernel_launch(void* const* d_in, const int* in_sizes, int n_in,
                              void* d_out, int out_size, void* d_ws, size_t ws_size,
                              hipStream_t stream) {
    const float* vertex_pos         = (const float*)d_in[0];
    const int*   faces              = (const int*)  d_in[1];
    const int*   vert_adj_faces     = (const int*)  d_in[2];
    const float* vert_adj_weights   = (const float*)d_in[3];
    const float* intrinsics         = (const float*)d_in[4];
    const float* extrinsics         = (const float*)d_in[5];
    const float* inverse_extrinsics = (const float*)d_in[6];
    const int*   face_id            = (const int*)  d_in[7];
    const float* barycentrics       = (const float*)d_in[8];
    float* out = (float*)d_out;
    char* ws = (char*)d_ws;
    const int TPB = 256;

    // packed-table layout: fn 4.8MB | pn 6.4MB | scr 12.8MB | faces4 3.2MB
    const size_t OFF_FN  = 0;
    const size_t OFF_PN  = 4800000;
    const size_t OFF_SCR = 11200000;
    const size_t OFF_F4  = 24000000;
    const size_t NEED    = 27200000;

    if (ws_size >= NEED) {
        float*  fn     = (float*) (ws + OFF_FN);
        float4* pn     = (float4*)(ws + OFF_PN);
        float4* scr    = (float4*)(ws + OFF_SCR);
        int4*   faces4 = (int4*)  (ws + OFF_F4);

        hipLaunchKernelGGL(k_face_normal, dim3((B_ * F_ + TPB - 1) / TPB), dim3(TPB), 0, stream,
                           vertex_pos, faces, fn);
        hipLaunchKernelGGL(k_faces4, dim3((F_ + TPB - 1) / TPB), dim3(TPB), 0, stream,
                           faces, faces4);
        hipLaunchKernelGGL(k_pn, dim3((B_ * V_ + TPB - 1) / TPB), dim3(TPB), 0, stream,
                           vertex_pos, fn, vert_adj_faces, vert_adj_weights, pn);
        hipLaunchKernelGGL(k_scr, dim3((B_ * C_ * V_ + TPB - 1) / TPB), dim3(TPB), 0, stream,
                           vertex_pos, intrinsics, extrinsics, scr);
        hipLaunchKernelGGL(k_pixel4, dim3((NPIX / 4 + TPB - 1) / TPB), dim3(TPB), 0, stream,
                           faces4, inverse_extrinsics, face_id, barycentrics, pn, scr, out);
    } else {
        float* face_normal   = (float*)(ws);
        float* vertex_normal = (float*)(ws + 4800000);
        float* iv            = (float*)(ws + 7200000);
        hipLaunchKernelGGL(k_face_normal, dim3((B_ * F_ + TPB - 1) / TPB), dim3(TPB), 0, stream,
                           vertex_pos, faces, face_normal);
        hipLaunchKernelGGL(k_vertex_normal, dim3((B_ * V_ + TPB - 1) / TPB), dim3(TPB), 0, stream,
                           face_normal, vert_adj_faces, vert_adj_weights, vertex_normal);
        hipLaunchKernelGGL(k_project, dim3((B_ * C_ * V_ + TPB - 1) / TPB), dim3(TPB), 0, stream,
                           vertex_pos, intrinsics, extrinsics, iv);
        hipLaunchKernelGGL(k_pixel, dim3((NPIX + TPB - 1) / TPB), dim3(TPB), 0, stream,
                           vertex_pos, faces, inverse_extrinsics, face_id, barycentrics,
                           vertex_normal, iv, out);
    }
}

// Round 4
// 111.231 us; speedup vs baseline: 1.3626x; 1.3626x over previous
//
#include <hip/hip_runtime.h>
#include <hip/hip_fp16.h>

#define B_ 2
#define C_ 4
#define H_ 512
#define W_ 512
#define V_ 100000
#define F_ 200000
#define A_ 8

#define HW_   (H_ * W_)                 // 262144
#define NPIX  (B_ * C_ * H_ * W_)       // 2,097,152
#define PLANE ((size_t)NPIX * 3)

// ---------------------------------------------------------------------------
// Kernel 1: face normals.  fn[b][f] = cross(v1-v0, v2-v0)   (B*F*3 floats)
// ---------------------------------------------------------------------------
__global__ void k_face_normal(const float* __restrict__ vertex_pos,
                              const int* __restrict__ faces,
                              float* __restrict__ face_normal) {
    int t = blockIdx.x * blockDim.x + threadIdx.x;
    if (t >= B_ * F_) return;
    int b = t / F_;
    int f = t - b * F_;
    int i0 = faces[f * 3 + 0];
    int i1 = faces[f * 3 + 1];
    int i2 = faces[f * 3 + 2];
    const float* vp = vertex_pos + (size_t)b * V_ * 3;
    float p0x = vp[i0 * 3 + 0], p0y = vp[i0 * 3 + 1], p0z = vp[i0 * 3 + 2];
    float p1x = vp[i1 * 3 + 0], p1y = vp[i1 * 3 + 1], p1z = vp[i1 * 3 + 2];
    float p2x = vp[i2 * 3 + 0], p2y = vp[i2 * 3 + 1], p2z = vp[i2 * 3 + 2];
    float e1x = p1x - p0x, e1y = p1y - p0y, e1z = p1z - p0z;
    float e2x = p2x - p0x, e2y = p2y - p0y, e2z = p2z - p0z;
    face_normal[(size_t)t * 3 + 0] = e1y * e2z - e1z * e2y;
    face_normal[(size_t)t * 3 + 1] = e1z * e2x - e1x * e2z;
    face_normal[(size_t)t * 3 + 2] = e1x * e2y - e1y * e2x;
}

// ---------------------------------------------------------------------------
// Kernel 2: faces packed into one u64 (3 x 17-bit vertex ids; V < 2^17)
// ---------------------------------------------------------------------------
__global__ void k_faces64(const int* __restrict__ faces,
                          unsigned long long* __restrict__ faces64) {
    int t = blockIdx.x * blockDim.x + threadIdx.x;
    if (t >= F_) return;
    unsigned long long i0 = (unsigned)faces[t * 3 + 0];
    unsigned long long i1 = (unsigned)faces[t * 3 + 1];
    unsigned long long i2 = (unsigned)faces[t * 3 + 2];
    faces64[t] = i0 | (i1 << 17) | (i2 << 34);
}

// ---------------------------------------------------------------------------
// Kernel 3: packed fp16 pos+normal table, 12 B/vertex:
//   pn[(b*V+v)*3 + {0,1,2}] = {h2(px,py), h2(pz,nx), h2(ny,nz)}
// ---------------------------------------------------------------------------
__global__ void k_pn16(const float* __restrict__ vertex_pos,
                       const float* __restrict__ face_normal,
                       const int* __restrict__ vert_adj_faces,
                       const float* __restrict__ vert_adj_weights,
                       unsigned int* __restrict__ pn) {
    int t = blockIdx.x * blockDim.x + threadIdx.x;
    if (t >= B_ * V_) return;
    int b = t / V_;
    int v = t - b * V_;
    const int* adj = vert_adj_faces + (size_t)v * A_;
    const float* wt = vert_adj_weights + (size_t)v * A_;
    const float* fn = face_normal + (size_t)b * F_ * 3;
    float ax = 0.f, ay = 0.f, az = 0.f;
#pragma unroll
    for (int a = 0; a < A_; ++a) {
        int f = adj[a];
        float w = wt[a];
        ax += w * fn[(size_t)f * 3 + 0];
        ay += w * fn[(size_t)f * 3 + 1];
        az += w * fn[(size_t)f * 3 + 2];
    }
    const float* p = vertex_pos + (size_t)t * 3;
    __half2 h0 = __floats2half2_rn(p[0], p[1]);
    __half2 h1 = __floats2half2_rn(p[2], ax);
    __half2 h2 = __floats2half2_rn(ay, az);
    unsigned int* o = pn + (size_t)t * 3;
    o[0] = *reinterpret_cast<unsigned int*>(&h0);
    o[1] = *reinterpret_cast<unsigned int*>(&h1);
    o[2] = *reinterpret_cast<unsigned int*>(&h2);
}

// ---------------------------------------------------------------------------
// Kernel 4: compact f32 screen table, 12 B/vertex/view: {ix/iz, iy/iz, iz}
// ---------------------------------------------------------------------------
__global__ void k_scr(const float* __restrict__ vertex_pos,
                      const float* __restrict__ intrinsics,
                      const float* __restrict__ extrinsics,
                      float* __restrict__ scr) {
    int t = blockIdx.x * blockDim.x + threadIdx.x;
    if (t >= B_ * C_ * V_) return;
    int v = t % V_;
    int bc = t / V_;
    int b = bc / C_;
    const float* vp = vertex_pos + ((size_t)b * V_ + v) * 3;
    float x = vp[0], y = vp[1], z = vp[2];
    const float* E = extrinsics + (size_t)bc * 12;
    float cv0 = x * E[0] + y * E[1] + z * E[2]  + E[3];
    float cv1 = x * E[4] + y * E[5] + z * E[6]  + E[7];
    float cv2 = x * E[8] + y * E[9] + z * E[10] + E[11];
    const float* K = intrinsics + (size_t)bc * 9;
    float i0 = cv0 * K[0] + cv1 * K[1] + cv2 * K[2];
    float i1 = cv0 * K[3] + cv1 * K[4] + cv2 * K[5];
    float i2 = cv0 * K[6] + cv1 * K[7] + cv2 * K[8];
    float* o = scr + (size_t)t * 3;
    o[0] = i0 / i2;
    o[1] = i1 / i2;
    o[2] = i2;
}

// ---------------------------------------------------------------------------
// Kernel 5: per-pixel shading. 1 px/thread. Streaming traffic is
// non-temporal so the gather tables (~4 MB/XCD) stay L2-resident.
// ---------------------------------------------------------------------------
__global__ __launch_bounds__(256) void k_pixel_nt(
        const unsigned long long* __restrict__ faces64,
        const float* __restrict__ inverse_extrinsics,
        const int* __restrict__ face_id,
        const float* __restrict__ bary,
        const unsigned int* __restrict__ pn,
        const float* __restrict__ scr,
        float* __restrict__ out) {
    int p = blockIdx.x * blockDim.x + threadIdx.x;
    if (p >= NPIX) return;
    int bc = p / HW_;
    int b = bc >> 2;   // C_ == 4

    int fid = __builtin_nontemporal_load(face_id + p);
    const float* bp = bary + (size_t)p * 3;
    float w0 = __builtin_nontemporal_load(bp + 0);
    float w1 = __builtin_nontemporal_load(bp + 1);
    float w2 = __builtin_nontemporal_load(bp + 2);

    float fg = 0.f, dd = 0.f;
    float px = 0.f, py = 0.f, pz = 0.f;
    float nx = 0.f, ny = 0.f, nz = 0.f;
    float sx = 0.f, sy = 0.f, sz = 0.f;

    if (fid >= 0) {
        unsigned long long f3 = faces64[fid];
        int i0 = (int)(f3 & 0x1FFFF);
        int i1 = (int)((f3 >> 17) & 0x1FFFF);
        int i2 = (int)((f3 >> 34) & 0x1FFFF);

        size_t base = (size_t)b * V_;
        const unsigned int* r0 = pn + (base + i0) * 3;
        const unsigned int* r1 = pn + (base + i1) * 3;
        const unsigned int* r2 = pn + (base + i2) * 3;
        unsigned int a0 = r0[0], a1 = r0[1], a2 = r0[2];
        unsigned int b0 = r1[0], b1 = r1[1], b2 = r1[2];
        unsigned int c0 = r2[0], c1 = r2[1], c2 = r2[2];

        float2 af0 = __half22float2(*reinterpret_cast<__half2*>(&a0));
        float2 af1 = __half22float2(*reinterpret_cast<__half2*>(&a1));
        float2 af2 = __half22float2(*reinterpret_cast<__half2*>(&a2));
        float2 bf0 = __half22float2(*reinterpret_cast<__half2*>(&b0));
        float2 bf1 = __half22float2(*reinterpret_cast<__half2*>(&b1));
        float2 bf2 = __half22float2(*reinterpret_cast<__half2*>(&b2));
        float2 cf0 = __half22float2(*reinterpret_cast<__half2*>(&c0));
        float2 cf1 = __half22float2(*reinterpret_cast<__half2*>(&c1));
        float2 cf2 = __half22float2(*reinterpret_cast<__half2*>(&c2));

        px = w0 * af0.x + w1 * bf0.x + w2 * cf0.x;
        py = w0 * af0.y + w1 * bf0.y + w2 * cf0.y;
        pz = w0 * af1.x + w1 * bf1.x + w2 * cf1.x;
        nx = w0 * af1.y + w1 * bf1.y + w2 * cf1.y;
        ny = w0 * af2.x + w1 * bf2.x + w2 * cf2.x;
        nz = w0 * af2.y + w1 * bf2.y + w2 * cf2.y;

        size_t sbase = (size_t)bc * V_;
        const float* s0 = scr + (sbase + i0) * 3;
        const float* s1 = scr + (sbase + i1) * 3;
        const float* s2 = scr + (sbase + i2) * 3;
        sx = w0 * s0[0] + w1 * s1[0] + w2 * s2[0];
        sy = w0 * s0[1] + w1 * s1[1] + w2 * s2[1];
        sz = w0 * s0[2] + w1 * s1[2] + w2 * s2[2];

        float nlen = fmaxf(sqrtf(nx * nx + ny * ny + nz * nz), 1e-12f);
        nx /= nlen; ny /= nlen; nz /= nlen;

        const float* ie = inverse_extrinsics + (size_t)bc * 16;
        float iw = ie[15];
        float dx = ie[3] / iw - px;
        float dy = ie[7] / iw - py;
        float dz = ie[11] / iw - pz;
        dd = sqrtf(dx * dx + dy * dy + dz * dz);
        fg = 1.f;
    }

    size_t o = (size_t)p * 3;
    float* o0 = out + 0 * PLANE + o;
    float* o1 = out + 1 * PLANE + o;
    float* o2 = out + 2 * PLANE + o;
    float* o3 = out + 3 * PLANE + o;
    float* o4 = out + 4 * PLANE + o;
    __builtin_nontemporal_store(fg, o0 + 0);
    __builtin_nontemporal_store(fg, o0 + 1);
    __builtin_nontemporal_store(fg, o0 + 2);
    __builtin_nontemporal_store(px, o1 + 0);
    __builtin_nontemporal_store(py, o1 + 1);
    __builtin_nontemporal_store(pz, o1 + 2);
    __builtin_nontemporal_store(nx, o2 + 0);
    __builtin_nontemporal_store(ny, o2 + 1);
    __builtin_nontemporal_store(nz, o2 + 2);
    __builtin_nontemporal_store(dd, o3 + 0);
    __builtin_nontemporal_store(dd, o3 + 1);
    __builtin_nontemporal_store(dd, o3 + 2);
    __builtin_nontemporal_store(sx, o4 + 0);
    __builtin_nontemporal_store(sy, o4 + 1);
    __builtin_nontemporal_store(sz, o4 + 2);
}

// ---------------------------------------------------------------------------
extern "C" void kernel_launch(void* const* d_in, const int* in_sizes, int n_in,
                              void* d_out, int out_size, void* d_ws, size_t ws_size,
                              hipStream_t stream) {
    const float* vertex_pos         = (const float*)d_in[0];
    const int*   faces              = (const int*)  d_in[1];
    const int*   vert_adj_faces     = (const int*)  d_in[2];
    const float* vert_adj_weights   = (const float*)d_in[3];
    const float* intrinsics         = (const float*)d_in[4];
    const float* extrinsics         = (const float*)d_in[5];
    const float* inverse_extrinsics = (const float*)d_in[6];
    const int*   face_id            = (const int*)  d_in[7];
    const float* barycentrics       = (const float*)d_in[8];
    float* out = (float*)d_out;
    char* ws = (char*)d_ws;
    const int TPB = 256;

    // layout: fn 4.8MB | faces64 1.6MB | pn16 2.4MB | scr 9.6MB = 18.4MB
    // (round-2 bench proved ws_size >= 27.2MB, so no fallback path needed)
    float*              fn      = (float*)             (ws + 0);
    unsigned long long* faces64 = (unsigned long long*)(ws + 4800000);
    unsigned int*       pn      = (unsigned int*)      (ws + 6400000);
    float*              scr     = (float*)             (ws + 8800000);

    hipLaunchKernelGGL(k_face_normal, dim3((B_ * F_ + TPB - 1) / TPB), dim3(TPB), 0, stream,
                       vertex_pos, faces, fn);
    hipLaunchKernelGGL(k_faces64, dim3((F_ + TPB - 1) / TPB), dim3(TPB), 0, stream,
                       faces, faces64);
    hipLaunchKernelGGL(k_pn16, dim3((B_ * V_ + TPB - 1) / TPB), dim3(TPB), 0, stream,
                       vertex_pos, fn, vert_adj_faces, vert_adj_weights, pn);
    hipLaunchKernelGGL(k_scr, dim3((B_ * C_ * V_ + TPB - 1) / TPB), dim3(TPB), 0, stream,
                       vertex_pos, intrinsics, extrinsics, scr);
    hipLaunchKernelGGL(k_pixel_nt, dim3(NPIX / TPB), dim3(TPB), 0, stream,
                       faces64, inverse_extrinsics, face_id, barycentrics, pn, scr, out);
}

// Round 5
// 107.801 us; speedup vs baseline: 1.4060x; 1.0318x over previous
//
#include <hip/hip_runtime.h>
#include <hip/hip_fp16.h>
#include <string.h>

#define B_ 2
#define C_ 4
#define H_ 512
#define W_ 512
#define V_ 100000
#define F_ 200000
#define A_ 8

#define HW_   (H_ * W_)                 // 262144 = 2^18
#define NPIX  (B_ * C_ * H_ * W_)       // 2,097,152
#define PLANE ((size_t)NPIX * 3)

__device__ __forceinline__ double pack2f(float a, float b) {
    float2 t = make_float2(a, b);
    double d;
    memcpy(&d, &t, 8);
    return d;
}
__device__ __forceinline__ float2 unpack2f(double d) {
    float2 t;
    memcpy(&t, &d, 8);
    return t;
}

// ---------------------------------------------------------------------------
// Prep 1 (fused): face normals (B*F) + faces64 pack (F)
//   fn[b][f] = cross(v1-v0, v2-v0);  faces64[f] = 3x17-bit vertex ids
// ---------------------------------------------------------------------------
__global__ void k_prep1(const float* __restrict__ vertex_pos,
                        const int* __restrict__ faces,
                        float* __restrict__ face_normal,
                        unsigned long long* __restrict__ faces64) {
    int t = blockIdx.x * blockDim.x + threadIdx.x;
    if (t >= B_ * F_) return;
    int b = t / F_;
    int f = t - b * F_;
    int i0 = faces[f * 3 + 0];
    int i1 = faces[f * 3 + 1];
    int i2 = faces[f * 3 + 2];
    if (b == 0) {
        faces64[f] = (unsigned long long)(unsigned)i0 |
                     ((unsigned long long)(unsigned)i1 << 17) |
                     ((unsigned long long)(unsigned)i2 << 34);
    }
    const float* vp = vertex_pos + (size_t)b * V_ * 3;
    float p0x = vp[i0 * 3 + 0], p0y = vp[i0 * 3 + 1], p0z = vp[i0 * 3 + 2];
    float p1x = vp[i1 * 3 + 0], p1y = vp[i1 * 3 + 1], p1z = vp[i1 * 3 + 2];
    float p2x = vp[i2 * 3 + 0], p2y = vp[i2 * 3 + 1], p2z = vp[i2 * 3 + 2];
    float e1x = p1x - p0x, e1y = p1y - p0y, e1z = p1z - p0z;
    float e2x = p2x - p0x, e2y = p2y - p0y, e2z = p2z - p0z;
    face_normal[(size_t)t * 3 + 0] = e1y * e2z - e1z * e2y;
    face_normal[(size_t)t * 3 + 1] = e1z * e2x - e1x * e2z;
    face_normal[(size_t)t * 3 + 2] = e1x * e2y - e1y * e2x;
}

// ---------------------------------------------------------------------------
// Prep 2 (fused): screen table (B*C*V, f32 12B) + fp16 pos+nrm table (B*V, 12B)
//   scr[bc*V+v] = {ix/iz, iy/iz, iz}
//   pn[(b*V+v)*3 + {0,1,2}] = {h2(px,py), h2(pz,nx), h2(ny,nz)}
// ---------------------------------------------------------------------------
__global__ void k_prep2(const float* __restrict__ vertex_pos,
                        const float* __restrict__ intrinsics,
                        const float* __restrict__ extrinsics,
                        const float* __restrict__ face_normal,
                        const int* __restrict__ vert_adj_faces,
                        const float* __restrict__ vert_adj_weights,
                        float* __restrict__ scr,
                        unsigned int* __restrict__ pn) {
    int t = blockIdx.x * blockDim.x + threadIdx.x;
    if (t >= B_ * C_ * V_) return;
    {   // screen-space projection
        int v = t % V_;
        int bc = t / V_;
        int b = bc / C_;
        const float* vp = vertex_pos + ((size_t)b * V_ + v) * 3;
        float x = vp[0], y = vp[1], z = vp[2];
        const float* E = extrinsics + (size_t)bc * 12;
        float cv0 = x * E[0] + y * E[1] + z * E[2]  + E[3];
        float cv1 = x * E[4] + y * E[5] + z * E[6]  + E[7];
        float cv2 = x * E[8] + y * E[9] + z * E[10] + E[11];
        const float* K = intrinsics + (size_t)bc * 9;
        float i0 = cv0 * K[0] + cv1 * K[1] + cv2 * K[2];
        float i1 = cv0 * K[3] + cv1 * K[4] + cv2 * K[5];
        float i2 = cv0 * K[6] + cv1 * K[7] + cv2 * K[8];
        float* o = scr + (size_t)t * 3;
        o[0] = i0 / i2;
        o[1] = i1 / i2;
        o[2] = i2;
    }
    if (t < B_ * V_) {  // vertex normal + fp16 pack
        int b = t / V_;
        int v = t - b * V_;
        const int* adj = vert_adj_faces + (size_t)v * A_;
        const float* wt = vert_adj_weights + (size_t)v * A_;
        const float* fn = face_normal + (size_t)b * F_ * 3;
        float ax = 0.f, ay = 0.f, az = 0.f;
#pragma unroll
        for (int a = 0; a < A_; ++a) {
            int f = adj[a];
            float w = wt[a];
            ax += w * fn[(size_t)f * 3 + 0];
            ay += w * fn[(size_t)f * 3 + 1];
            az += w * fn[(size_t)f * 3 + 2];
        }
        const float* p = vertex_pos + (size_t)t * 3;
        __half2 h0 = __floats2half2_rn(p[0], p[1]);
        __half2 h1 = __floats2half2_rn(p[2], ax);
        __half2 h2 = __floats2half2_rn(ay, az);
        unsigned int* o = pn + (size_t)t * 3;
        o[0] = *reinterpret_cast<unsigned int*>(&h0);
        o[1] = *reinterpret_cast<unsigned int*>(&h1);
        o[2] = *reinterpret_cast<unsigned int*>(&h2);
    }
}

// ---------------------------------------------------------------------------
// Pixel kernel: 2 px/thread, chunked XCD swizzle (each XCD works one view ->
// per-XCD L2 set = faces64 1.6 + pn 1.2 + scr 1.2 = 4.0 MB), NT stream I/O.
// ---------------------------------------------------------------------------
__global__ __launch_bounds__(256) void k_pixel2(
        const unsigned long long* __restrict__ faces64,
        const float* __restrict__ inverse_extrinsics,
        const int* __restrict__ face_id,
        const float* __restrict__ bary,
        const unsigned int* __restrict__ pn,
        const float* __restrict__ scr,
        float* __restrict__ out) {
    // chunked XCD swizzle: 4096 blocks, 8 XCDs -> 512 contiguous blocks/XCD
    int nb = gridDim.x;
    int cpx = nb >> 3;
    int bid = blockIdx.x;
    int swz = (bid & 7) * cpx + (bid >> 3);

    int base = (swz * 256 + (int)threadIdx.x) * 2;   // first of 2 pixels
    int bc = base >> 18;        // HW_ = 2^18; both pixels in same view
    int b  = bc >> 2;           // C_ == 4

    // camera origin (uniform within block)
    const float* ie = inverse_extrinsics + (size_t)bc * 16;
    float iw = ie[15];
    float ox = ie[3] / iw, oy = ie[7] / iw, oz = ie[11] / iw;

    // streaming loads (8B, non-temporal)
    long long fid2 = __builtin_nontemporal_load((const long long*)(face_id + base));
    int fidv[2] = { (int)(fid2 & 0xFFFFFFFFll), (int)(fid2 >> 32) };

    const double* bp = (const double*)(bary + (size_t)base * 3);  // 24B-aligned
    float2 q0 = unpack2f(__builtin_nontemporal_load(bp + 0));
    float2 q1 = unpack2f(__builtin_nontemporal_load(bp + 1));
    float2 q2 = unpack2f(__builtin_nontemporal_load(bp + 2));
    float bw[2][3] = {{q0.x, q0.y, q1.x}, {q1.y, q2.x, q2.y}};

    float fg[2], dep[2];
    float pos[2][3], nrm[2][3], sc[2][3];

#pragma unroll
    for (int k = 0; k < 2; ++k) {
        int fid = fidv[k];
        float w0 = bw[k][0], w1 = bw[k][1], w2 = bw[k][2];
        if (fid >= 0) {
            unsigned long long f3 = faces64[fid];
            int i0 = (int)(f3 & 0x1FFFF);
            int i1 = (int)((f3 >> 17) & 0x1FFFF);
            int i2 = (int)((f3 >> 34) & 0x1FFFF);

            size_t basev = (size_t)b * V_;
            const unsigned int* r0 = pn + (basev + i0) * 3;
            const unsigned int* r1 = pn + (basev + i1) * 3;
            const unsigned int* r2 = pn + (basev + i2) * 3;
            unsigned int a0 = r0[0], a1 = r0[1], a2 = r0[2];
            unsigned int b0 = r1[0], b1 = r1[1], b2 = r1[2];
            unsigned int c0 = r2[0], c1 = r2[1], c2 = r2[2];

            float2 af0 = __half22float2(*reinterpret_cast<__half2*>(&a0));
            float2 af1 = __half22float2(*reinterpret_cast<__half2*>(&a1));
            float2 af2 = __half22float2(*reinterpret_cast<__half2*>(&a2));
            float2 bf0 = __half22float2(*reinterpret_cast<__half2*>(&b0));
            float2 bf1 = __half22float2(*reinterpret_cast<__half2*>(&b1));
            float2 bf2 = __half22float2(*reinterpret_cast<__half2*>(&b2));
            float2 cf0 = __half22float2(*reinterpret_cast<__half2*>(&c0));
            float2 cf1 = __half22float2(*reinterpret_cast<__half2*>(&c1));
            float2 cf2 = __half22float2(*reinterpret_cast<__half2*>(&c2));

            float px = w0 * af0.x + w1 * bf0.x + w2 * cf0.x;
            float py = w0 * af0.y + w1 * bf0.y + w2 * cf0.y;
            float pz = w0 * af1.x + w1 * bf1.x + w2 * cf1.x;
            float nx = w0 * af1.y + w1 * bf1.y + w2 * cf1.y;
            float ny = w0 * af2.x + w1 * bf2.x + w2 * cf2.x;
            float nz = w0 * af2.y + w1 * bf2.y + w2 * cf2.y;

            size_t sbase = (size_t)bc * V_;
            const float* s0 = scr + (sbase + i0) * 3;
            const float* s1 = scr + (sbase + i1) * 3;
            const float* s2 = scr + (sbase + i2) * 3;
            float sx = w0 * s0[0] + w1 * s1[0] + w2 * s2[0];
            float sy = w0 * s0[1] + w1 * s1[1] + w2 * s2[1];
            float sz = w0 * s0[2] + w1 * s1[2] + w2 * s2[2];

            float nlen = fmaxf(sqrtf(nx * nx + ny * ny + nz * nz), 1e-12f);
            nx /= nlen; ny /= nlen; nz /= nlen;

            float dx = ox - px, dy = oy - py, dz = oz - pz;
            fg[k] = 1.f;
            dep[k] = sqrtf(dx * dx + dy * dy + dz * dz);
            pos[k][0] = px; pos[k][1] = py; pos[k][2] = pz;
            nrm[k][0] = nx; nrm[k][1] = ny; nrm[k][2] = nz;
            sc[k][0] = sx; sc[k][1] = sy; sc[k][2] = sz;
        } else {
            fg[k] = 0.f; dep[k] = 0.f;
            pos[k][0] = pos[k][1] = pos[k][2] = 0.f;
            nrm[k][0] = nrm[k][1] = nrm[k][2] = 0.f;
            sc[k][0] = sc[k][1] = sc[k][2] = 0.f;
        }
    }

    // 6 floats per plane per thread, written as 3x 8B NT stores (24B-aligned)
    size_t o = (size_t)base * 3;
    double* o0 = (double*)(out + 0 * PLANE + o);
    double* o1 = (double*)(out + 1 * PLANE + o);
    double* o2 = (double*)(out + 2 * PLANE + o);
    double* o3 = (double*)(out + 3 * PLANE + o);
    double* o4 = (double*)(out + 4 * PLANE + o);
    __builtin_nontemporal_store(pack2f(fg[0], fg[0]), o0 + 0);
    __builtin_nontemporal_store(pack2f(fg[0], fg[1]), o0 + 1);
    __builtin_nontemporal_store(pack2f(fg[1], fg[1]), o0 + 2);
    __builtin_nontemporal_store(pack2f(pos[0][0], pos[0][1]), o1 + 0);
    __builtin_nontemporal_store(pack2f(pos[0][2], pos[1][0]), o1 + 1);
    __builtin_nontemporal_store(pack2f(pos[1][1], pos[1][2]), o1 + 2);
    __builtin_nontemporal_store(pack2f(nrm[0][0], nrm[0][1]), o2 + 0);
    __builtin_nontemporal_store(pack2f(nrm[0][2], nrm[1][0]), o2 + 1);
    __builtin_nontemporal_store(pack2f(nrm[1][1], nrm[1][2]), o2 + 2);
    __builtin_nontemporal_store(pack2f(dep[0], dep[0]), o3 + 0);
    __builtin_nontemporal_store(pack2f(dep[0], dep[1]), o3 + 1);
    __builtin_nontemporal_store(pack2f(dep[1], dep[1]), o3 + 2);
    __builtin_nontemporal_store(pack2f(sc[0][0], sc[0][1]), o4 + 0);
    __builtin_nontemporal_store(pack2f(sc[0][2], sc[1][0]), o4 + 1);
    __builtin_nontemporal_store(pack2f(sc[1][1], sc[1][2]), o4 + 2);
}

// ---------------------------------------------------------------------------
extern "C" void kernel_launch(void* const* d_in, const int* in_sizes, int n_in,
                              void* d_out, int out_size, void* d_ws, size_t ws_size,
                              hipStream_t stream) {
    const float* vertex_pos         = (const float*)d_in[0];
    const int*   faces              = (const int*)  d_in[1];
    const int*   vert_adj_faces     = (const int*)  d_in[2];
    const float* vert_adj_weights   = (const float*)d_in[3];
    const float* intrinsics         = (const float*)d_in[4];
    const float* extrinsics         = (const float*)d_in[5];
    const float* inverse_extrinsics = (const float*)d_in[6];
    const int*   face_id            = (const int*)  d_in[7];
    const float* barycentrics       = (const float*)d_in[8];
    float* out = (float*)d_out;
    char* ws = (char*)d_ws;
    const int TPB = 256;

    // layout: fn 4.8MB | faces64 1.6MB | pn16 2.4MB | scr 9.6MB = 18.4MB
    float*              fn      = (float*)             (ws + 0);
    unsigned long long* faces64 = (unsigned long long*)(ws + 4800000);
    unsigned int*       pn      = (unsigned int*)      (ws + 6400000);
    float*              scr     = (float*)             (ws + 8800000);

    hipLaunchKernelGGL(k_prep1, dim3((B_ * F_ + TPB - 1) / TPB), dim3(TPB), 0, stream,
                       vertex_pos, faces, fn, faces64);
    hipLaunchKernelGGL(k_prep2, dim3((B_ * C_ * V_ + TPB - 1) / TPB), dim3(TPB), 0, stream,
                       vertex_pos, intrinsics, extrinsics, fn,
                       vert_adj_faces, vert_adj_weights, scr, pn);
    hipLaunchKernelGGL(k_pixel2, dim3(NPIX / 2 / TPB), dim3(TPB), 0, stream,
                       faces64, inverse_extrinsics, face_id, barycentrics, pn, scr, out);
}